// Round 1
// baseline (627.822 us; speedup 1.0000x reference)
//
#include <hip/hip_runtime.h>
#include <cstddef>

namespace {

constexpr int kH = 1024;
constexpr int kFF = 4096;
constexpr int kB = 8;
constexpr int kL = 12;
constexpr float kEps = 1e-5f;

struct StackParams {
  const float *inw, *inb, *ow, *ob, *g1, *be1, *g2, *be2, *W1, *b1, *W2, *b2;
};

__device__ __forceinline__ void blkReduceSum2(float& a, float& c, float* red) {
#pragma unroll
  for (int m = 1; m < 64; m <<= 1) { a += __shfl_xor(a, m); c += __shfl_xor(c, m); }
  int w = threadIdx.x >> 6;
  __syncthreads();
  if ((threadIdx.x & 63) == 0) { red[w] = a; red[4 + w] = c; }
  __syncthreads();
  a = red[0] + red[1] + red[2] + red[3];
  c = red[4] + red[5] + red[6] + red[7];
}

__device__ __forceinline__ void blkReduceMaxMin(float& a, float& c, float* red) {
#pragma unroll
  for (int m = 1; m < 64; m <<= 1) {
    a = fmaxf(a, __shfl_xor(a, m));
    c = fminf(c, __shfl_xor(c, m));
  }
  int w = threadIdx.x >> 6;
  __syncthreads();
  if ((threadIdx.x & 63) == 0) { red[w] = a; red[4 + w] = c; }
  __syncthreads();
  a = fmaxf(fmaxf(red[0], red[1]), fmaxf(red[2], red[3]));
  c = fminf(fminf(red[4], red[5]), fminf(red[6], red[7]));
}

// Partial batched GEMV: part[kc][b][n] = sum_{k in chunk kc} X[b][k] * W[k][n]
template <int KC>
__global__ __launch_bounds__(256) void gemvPart(const float* __restrict__ X,
                                                const float* __restrict__ W,
                                                float* __restrict__ part,
                                                int K, int N) {
  const int FT = N >> 10;            // 1024 cols per workgroup (256 thr * 4)
  int ft = blockIdx.x % FT;
  int kc = blockIdx.x / FT;
  int k0 = kc * KC;
  __shared__ float Xs[kB][KC];
  int t = threadIdx.x;
  for (int i = t; i < kB * KC; i += 256) {
    int b = i / KC, kk = i % KC;
    Xs[b][kk] = X[(size_t)b * K + k0 + kk];
  }
  __syncthreads();
  int c0 = (ft << 10) + (t << 2);
  float acc[kB][4];
#pragma unroll
  for (int b = 0; b < kB; ++b)
#pragma unroll
    for (int j = 0; j < 4; ++j) acc[b][j] = 0.f;
  const float* Wp = W + (size_t)k0 * N + c0;
#pragma unroll
  for (int kk = 0; kk < KC; ++kk) {
    float4 w = *reinterpret_cast<const float4*>(Wp + (size_t)kk * N);
#pragma unroll
    for (int b = 0; b < kB; ++b) {
      float x = Xs[b][kk];
      acc[b][0] = fmaf(x, w.x, acc[b][0]);
      acc[b][1] = fmaf(x, w.y, acc[b][1]);
      acc[b][2] = fmaf(x, w.z, acc[b][2]);
      acc[b][3] = fmaf(x, w.w, acc[b][3]);
    }
  }
  float* pp = part + (size_t)kc * kB * N + c0;
#pragma unroll
  for (int b = 0; b < kB; ++b) {
    *reinterpret_cast<float4*>(pp + (size_t)b * N) =
        make_float4(acc[b][0], acc[b][1], acc[b][2], acc[b][3]);
  }
}

// emb[0]=cte, emb[1]=cle ; kv initialized identically.
__global__ __launch_bounds__(256) void embedReduce(const float* __restrict__ pct,
                                                   const float* __restrict__ pcl,
                                                   const float* __restrict__ b_ct,
                                                   const float* __restrict__ b_cl,
                                                   float* __restrict__ emb,
                                                   float* __restrict__ kv) {
  int id = blockIdx.x * 256 + threadIdx.x;  // 0..16383
  int s = id >> 13;
  int bn = id & 8191;
  int n = id & 1023;
  float sum;
  if (s == 0) {
    sum = b_ct[n];
#pragma unroll 4
    for (int p = 0; p < 128; ++p) sum += pct[(size_t)p * 8192 + bn];
  } else {
    sum = b_cl[n];
#pragma unroll 4
    for (int p = 0; p < 32; ++p) sum += pcl[(size_t)p * 8192 + bn];
  }
  emb[id] = sum;
  kv[id] = sum;
}

// LN1 + scalar projections + rank-1 softmax attention + out-proj + residual.
// y2[s][b][q] = av*ow + ob + v[q]
__global__ __launch_bounds__(256) void attnKernel(const float* __restrict__ kv,
                                                  const float* __restrict__ emb,
                                                  float* __restrict__ y2,
                                                  StackParams P0, StackParams P1,
                                                  int l) {
  int bid = blockIdx.x;      // 512 = 2 s * 8 b * 32 qt
  int s = bid >> 8;
  int b = (bid >> 5) & 7;
  int qt = bid & 31;
  StackParams P = s ? P1 : P0;
  const float* kvr = kv + ((size_t)((s << 3) + b)) * kH;
  const float* qr = emb + ((size_t)(((1 - s) << 3) + b)) * kH;   // query = other embedding
  float wi0 = P.inw[l * 3 + 0], wi1 = P.inw[l * 3 + 1], wi2 = P.inw[l * 3 + 2];
  float bi0 = P.inb[l * 3 + 0], bi1 = P.inb[l * 3 + 1], bi2 = P.inb[l * 3 + 2];
  float ow = P.ow[l], ob = P.ob[l];
  const float* g1 = P.g1 + (size_t)l * kH;
  const float* be1 = P.be1 + (size_t)l * kH;

  __shared__ float kvs[kH];
  __shared__ float2 kvp[kH];   // (kp, vp)
  __shared__ float red[8];

  int t = threadIdx.x;
  float lsum = 0.f, lsq = 0.f;
#pragma unroll
  for (int i = 0; i < 4; ++i) {
    float x = kvr[t + 256 * i];
    kvs[t + 256 * i] = x;
    lsum += x;
    lsq += x * x;
  }
  blkReduceSum2(lsum, lsq, red);
  float mean = lsum * (1.f / kH);
  float rstd = rsqrtf(lsq * (1.f / kH) - mean * mean + kEps);

  float lmax = -1e30f, lmin = 1e30f;
#pragma unroll
  for (int i = 0; i < 4; ++i) {
    int k = t + 256 * i;
    float x = kvs[k];
    float kp = fmaf(x, wi1, bi1);
    float v = (x - mean) * rstd * g1[k] + be1[k];
    float vp = fmaf(v, wi2, bi2);
    kvp[k] = make_float2(kp, vp);
    lmax = fmaxf(lmax, kp);
    lmin = fminf(lmin, kp);
  }
  blkReduceMaxMin(lmax, lmin, red);
  __syncthreads();

  int q = (qt << 5) + (t >> 3);
  int ks = t & 7;
  float sq = fmaf(qr[q], wi0, bi0);
  float mb = fmaxf(sq * lmax, sq * lmin);
  float den0 = 0.f, num0 = 0.f, den1 = 0.f, num1 = 0.f;
#pragma unroll 4
  for (int j = 0; j < 128; j += 2) {
    float2 a = kvp[ks + (j << 3)];
    float2 c = kvp[ks + ((j + 1) << 3)];
    float e0 = __expf(fmaf(sq, a.x, -mb));
    float e1 = __expf(fmaf(sq, c.x, -mb));
    den0 += e0; num0 = fmaf(e0, a.y, num0);
    den1 += e1; num1 = fmaf(e1, c.y, num1);
  }
  float den = den0 + den1, num = num0 + num1;
#pragma unroll
  for (int m = 1; m < 8; m <<= 1) {
    den += __shfl_xor(den, m);
    num += __shfl_xor(num, m);
  }
  if (ks == 0) {
    float av = num / den;
    float vq = (kvs[q] - mean) * rstd * g1[q] + be1[q];
    y2[((size_t)((s << 3) + b)) * kH + q] = fmaf(av, ow, ob) + vq;
  }
}

// LN2 (stats recomputed per WG) + normalize chunk + partial GEMV vs W1.
__global__ __launch_bounds__(256) void gemm1Kernel(const float* __restrict__ y2,
                                                   float* __restrict__ xn,
                                                   float* __restrict__ part1,
                                                   StackParams P0, StackParams P1,
                                                   int l) {
  int bid = blockIdx.x;      // 512 = 2 s * 4 ft * 64 kc
  int s = bid >> 8;
  int ft = (bid >> 6) & 3;
  int kc = bid & 63;
  StackParams P = s ? P1 : P0;
  const float* y2s = y2 + ((size_t)s << 13);
  __shared__ float sm[kB], sr[kB];
  __shared__ float Xs[kB][16];
  int t = threadIdx.x;
  {
    int b = t >> 5, lane = t & 31;
    const float* row = y2s + (size_t)b * kH;
    float sum = 0.f, sq = 0.f;
    for (int i = lane; i < kH; i += 32) {
      float x = row[i];
      sum += x;
      sq += x * x;
    }
#pragma unroll
    for (int m = 1; m < 32; m <<= 1) { sum += __shfl_xor(sum, m); sq += __shfl_xor(sq, m); }
    if (lane == 0) {
      float mean = sum * (1.f / kH);
      sm[b] = mean;
      sr[b] = rsqrtf(sq * (1.f / kH) - mean * mean + kEps);
    }
  }
  __syncthreads();
  int k0 = kc << 4;
  if (t < 128) {
    int b = t >> 4, kk = t & 15, k = k0 + kk;
    float x = y2s[(size_t)b * kH + k];
    float v = (x - sm[b]) * sr[b] * P.g2[(size_t)l * kH + k] + P.be2[(size_t)l * kH + k];
    Xs[b][kk] = v;
    if (ft == 0) xn[((size_t)s << 13) + (size_t)b * kH + k] = v;
  }
  __syncthreads();
  int c0 = (ft << 10) + (t << 2);
  const float* W = P.W1 + (size_t)l * kH * kFF + (size_t)k0 * kFF + c0;
  float acc[kB][4];
#pragma unroll
  for (int b = 0; b < kB; ++b)
#pragma unroll
    for (int j = 0; j < 4; ++j) acc[b][j] = 0.f;
#pragma unroll
  for (int kk = 0; kk < 16; ++kk) {
    float4 w = *reinterpret_cast<const float4*>(W + (size_t)kk * kFF);
#pragma unroll
    for (int b = 0; b < kB; ++b) {
      float x = Xs[b][kk];
      acc[b][0] = fmaf(x, w.x, acc[b][0]);
      acc[b][1] = fmaf(x, w.y, acc[b][1]);
      acc[b][2] = fmaf(x, w.z, acc[b][2]);
      acc[b][3] = fmaf(x, w.w, acc[b][3]);
    }
  }
  float* pp = part1 + ((size_t)(s * 64 + kc) * kB) * kFF + c0;
#pragma unroll
  for (int b = 0; b < kB; ++b) {
    *reinterpret_cast<float4*>(pp + (size_t)b * kFF) =
        make_float4(acc[b][0], acc[b][1], acc[b][2], acc[b][3]);
  }
}

// Reduce h partials for chunk + bias1 + exact gelu, then partial GEMV vs W2.
__global__ __launch_bounds__(256) void gemm2Kernel(const float* __restrict__ part1,
                                                   float* __restrict__ part2,
                                                   StackParams P0, StackParams P1,
                                                   int l) {
  int bid = blockIdx.x;      // 512 = 2 s * 256 kc
  int s = bid >> 8;
  int kc = bid & 255;
  StackParams P = s ? P1 : P0;
  int k0 = kc << 4;
  __shared__ float Xs[kB][16];
  int t = threadIdx.x;
  if (t < 128) {
    int b = t >> 4, kk = t & 15;
    const float* pp = part1 + (size_t)s * 64 * kB * kFF + (size_t)b * kFF + k0 + kk;
    float sum = P.b1[(size_t)l * kFF + k0 + kk];
#pragma unroll 8
    for (int p = 0; p < 64; ++p) sum += pp[(size_t)p * kB * kFF];
    Xs[b][kk] = 0.5f * sum * (1.f + erff(sum * 0.70710678118654752f));
  }
  __syncthreads();
  int c0 = t << 2;
  const float* W = P.W2 + (size_t)l * kFF * kH + (size_t)k0 * kH + c0;
  float acc[kB][4];
#pragma unroll
  for (int b = 0; b < kB; ++b)
#pragma unroll
    for (int j = 0; j < 4; ++j) acc[b][j] = 0.f;
#pragma unroll
  for (int kk = 0; kk < 16; ++kk) {
    float4 w = *reinterpret_cast<const float4*>(W + (size_t)kk * kH);
#pragma unroll
    for (int b = 0; b < kB; ++b) {
      float x = Xs[b][kk];
      acc[b][0] = fmaf(x, w.x, acc[b][0]);
      acc[b][1] = fmaf(x, w.y, acc[b][1]);
      acc[b][2] = fmaf(x, w.z, acc[b][2]);
      acc[b][3] = fmaf(x, w.w, acc[b][3]);
    }
  }
  float* pp = part2 + ((size_t)(s * 256 + kc) * kB) * kH + c0;
#pragma unroll
  for (int b = 0; b < kB; ++b) {
    *reinterpret_cast<float4*>(pp + (size_t)b * kH) =
        make_float4(acc[b][0], acc[b][1], acc[b][2], acc[b][3]);
  }
}

// kv_new = sum_p part2 + b2 + xn (residual)
__global__ __launch_bounds__(256) void reduce2Kernel(const float* __restrict__ part2,
                                                     const float* __restrict__ xn,
                                                     float* __restrict__ kv,
                                                     StackParams P0, StackParams P1,
                                                     int l) {
  int gid = blockIdx.x * 256 + threadIdx.x;   // 65536 = 16384 outputs * 4 lanes
  int o = gid >> 2;
  int ks = gid & 3;
  int s = o >> 13;
  int bn = o & 8191;
  int n = o & 1023;
  const float* pp = part2 + (size_t)s * 256 * 8192 + (size_t)ks * 8192 + bn;
  float sum = 0.f;
#pragma unroll 8
  for (int j = 0; j < 64; ++j) sum += pp[(size_t)j * 4 * 8192];
  sum += __shfl_xor(sum, 1);
  sum += __shfl_xor(sum, 2);
  if (ks == 0) {
    StackParams P = s ? P1 : P0;
    kv[o] = sum + P.b2[(size_t)l * kH + n] + xn[o];
  }
}

__global__ __launch_bounds__(256) void finalLn(const float* __restrict__ kv,
                                               const float* __restrict__ g,
                                               const float* __restrict__ bb,
                                               float* __restrict__ out) {
  int b = blockIdx.x;   // 8
  int t = threadIdx.x;
  __shared__ float red[8];
  float vals[8];
  float sum = 0.f, sq = 0.f;
#pragma unroll
  for (int i = 0; i < 8; ++i) {
    int idx = t + 256 * i;          // 0..2047
    int s = idx >> 10, n = idx & 1023;
    float x = kv[(size_t)s * 8192 + (size_t)b * kH + n];
    vals[i] = x;
    sum += x;
    sq += x * x;
  }
  blkReduceSum2(sum, sq, red);
  float mean = sum * (1.f / 2048.f);
  float rstd = rsqrtf(sq * (1.f / 2048.f) - mean * mean + kEps);
#pragma unroll
  for (int i = 0; i < 8; ++i) {
    int idx = t + 256 * i;
    out[(size_t)b * 2048 + idx] = (vals[i] - mean) * rstd * g[idx] + bb[idx];
  }
}

}  // namespace

extern "C" void kernel_launch(void* const* d_in, const int* in_sizes, int n_in,
                              void* d_out, int out_size, void* d_ws, size_t ws_size,
                              hipStream_t stream) {
  const float* ct = (const float*)d_in[0];
  const float* clinical = (const float*)d_in[1];
  const float* W_ct = (const float*)d_in[2];
  const float* b_ct = (const float*)d_in[3];
  const float* W_cl = (const float*)d_in[4];
  const float* b_cl = (const float*)d_in[5];
  const float* norm_g = (const float*)d_in[6];
  const float* norm_b = (const float*)d_in[7];

  StackParams P0{(const float*)d_in[8],  (const float*)d_in[9],  (const float*)d_in[10],
                 (const float*)d_in[11], (const float*)d_in[12], (const float*)d_in[13],
                 (const float*)d_in[14], (const float*)d_in[15], (const float*)d_in[16],
                 (const float*)d_in[17], (const float*)d_in[18], (const float*)d_in[19]};
  StackParams P1{(const float*)d_in[20], (const float*)d_in[21], (const float*)d_in[22],
                 (const float*)d_in[23], (const float*)d_in[24], (const float*)d_in[25],
                 (const float*)d_in[26], (const float*)d_in[27], (const float*)d_in[28],
                 (const float*)d_in[29], (const float*)d_in[30], (const float*)d_in[31]};

  float* ws = (float*)d_ws;
  float* emb = ws;                                   // [2][8][1024]
  float* kv = emb + 2 * kB * kH;                     // [2][8][1024]
  float* y2 = kv + 2 * kB * kH;                      // [2][8][1024]
  float* xn = y2 + 2 * kB * kH;                      // [2][8][1024]
  float* part1 = xn + 2 * kB * kH;                   // [2][64][8][4096] = 16 MB
  float* part2 = part1 + (size_t)2 * 64 * kB * kFF;  // [2][256][8][1024] = 16 MB
  float* pct = part1;                                // reuse: [128][8][1024]
  float* pcl = part1 + (size_t)128 * kB * kH;        // [32][8][1024]

  // Embeddings: cte = ct @ W_ct + b_ct ; cle = clinical @ W_cl + b_cl
  gemvPart<16><<<128, 256, 0, stream>>>(ct, W_ct, pct, 2048, 1024);
  gemvPart<4><<<32, 256, 0, stream>>>(clinical, W_cl, pcl, 128, 1024);
  embedReduce<<<64, 256, 0, stream>>>(pct, pcl, b_ct, b_cl, emb, kv);

  for (int l = 0; l < kL; ++l) {
    attnKernel<<<512, 256, 0, stream>>>(kv, emb, y2, P0, P1, l);
    gemm1Kernel<<<512, 256, 0, stream>>>(y2, xn, part1, P0, P1, l);
    gemm2Kernel<<<512, 256, 0, stream>>>(part1, part2, P0, P1, l);
    reduce2Kernel<<<256, 256, 0, stream>>>(part2, xn, kv, P0, P1, l);
  }

  finalLn<<<8, 256, 0, stream>>>(kv, norm_g, norm_b, (float*)d_out);
}

// Round 2
// 578.398 us; speedup vs baseline: 1.0854x; 1.0854x over previous
//
#include <hip/hip_runtime.h>
#include <cstddef>

namespace {

constexpr int kH = 1024;
constexpr int kFF = 4096;
constexpr int kB = 8;
constexpr int kL = 12;
constexpr float kEps = 1e-5f;

struct StackParams {
  const float *inw, *inb, *ow, *ob, *g1, *be1, *g2, *be2, *W1, *b1, *W2, *b2;
};

__device__ __forceinline__ void blkReduceSum2(float& a, float& c, float* red) {
#pragma unroll
  for (int m = 1; m < 64; m <<= 1) { a += __shfl_xor(a, m); c += __shfl_xor(c, m); }
  int w = threadIdx.x >> 6;
  __syncthreads();
  if ((threadIdx.x & 63) == 0) { red[w] = a; red[4 + w] = c; }
  __syncthreads();
  a = red[0] + red[1] + red[2] + red[3];
  c = red[4] + red[5] + red[6] + red[7];
}

__device__ __forceinline__ void blkReduceMaxMin(float& a, float& c, float* red) {
#pragma unroll
  for (int m = 1; m < 64; m <<= 1) {
    a = fmaxf(a, __shfl_xor(a, m));
    c = fminf(c, __shfl_xor(c, m));
  }
  int w = threadIdx.x >> 6;
  __syncthreads();
  if ((threadIdx.x & 63) == 0) { red[w] = a; red[4 + w] = c; }
  __syncthreads();
  a = fmaxf(fmaxf(red[0], red[1]), fmaxf(red[2], red[3]));
  c = fminf(fminf(red[4], red[5]), fminf(red[6], red[7]));
}

// Partial batched GEMV for embeddings: part[kc][b][n] = sum_{k in chunk} X[b][k]*W[k][n]
template <int KC>
__global__ __launch_bounds__(256) void gemvPart(const float* __restrict__ X,
                                                const float* __restrict__ W,
                                                float* __restrict__ part,
                                                int K, int N) {
  const int FT = N >> 10;
  int ft = blockIdx.x % FT;
  int kc = blockIdx.x / FT;
  int k0 = kc * KC;
  __shared__ float Xs[kB][KC];
  int t = threadIdx.x;
  for (int i = t; i < kB * KC; i += 256) {
    int b = i / KC, kk = i % KC;
    Xs[b][kk] = X[(size_t)b * K + k0 + kk];
  }
  __syncthreads();
  int c0 = (ft << 10) + (t << 2);
  float acc[kB][4];
#pragma unroll
  for (int b = 0; b < kB; ++b)
#pragma unroll
    for (int j = 0; j < 4; ++j) acc[b][j] = 0.f;
  const float* Wp = W + (size_t)k0 * N + c0;
#pragma unroll
  for (int kk = 0; kk < KC; ++kk) {
    float4 w = *reinterpret_cast<const float4*>(Wp + (size_t)kk * N);
#pragma unroll
    for (int b = 0; b < kB; ++b) {
      float x = Xs[b][kk];
      acc[b][0] = fmaf(x, w.x, acc[b][0]);
      acc[b][1] = fmaf(x, w.y, acc[b][1]);
      acc[b][2] = fmaf(x, w.z, acc[b][2]);
      acc[b][3] = fmaf(x, w.w, acc[b][3]);
    }
  }
  float* pp = part + (size_t)kc * kB * N + c0;
#pragma unroll
  for (int b = 0; b < kB; ++b) {
    *reinterpret_cast<float4*>(pp + (size_t)b * N) =
        make_float4(acc[b][0], acc[b][1], acc[b][2], acc[b][3]);
  }
}

__global__ __launch_bounds__(256) void embedReduce(const float* __restrict__ pct,
                                                   const float* __restrict__ pcl,
                                                   const float* __restrict__ b_ct,
                                                   const float* __restrict__ b_cl,
                                                   float* __restrict__ emb,
                                                   float* __restrict__ kv0) {
  int id = blockIdx.x * 256 + threadIdx.x;  // 0..16383
  int s = id >> 13;
  int bn = id & 8191;
  int n = id & 1023;
  float sum;
  if (s == 0) {
    sum = b_ct[n];
#pragma unroll 4
    for (int p = 0; p < 128; ++p) sum += pct[(size_t)p * 8192 + bn];
  } else {
    sum = b_cl[n];
#pragma unroll 4
    for (int p = 0; p < 32; ++p) sum += pcl[(size_t)p * 8192 + bn];
  }
  emb[id] = sum;
  kv0[id] = sum;
}

// Fused: (l>0) kv reconstruction from part2(16 slices)+b2+xn, then LN1 +
// scalar projections + rank-1 softmax attention + out-proj + residual.
__global__ __launch_bounds__(256) void attnKernel(const float* __restrict__ kv0,
                                                  const float* __restrict__ part2,
                                                  const float* __restrict__ xn,
                                                  const float* __restrict__ emb,
                                                  float* __restrict__ y2,
                                                  StackParams P0, StackParams P1,
                                                  int l) {
  int bid = blockIdx.x;      // 512 = 2 s * 8 b * 32 qt
  int s = bid >> 8;
  int b = (bid >> 5) & 7;
  int qt = bid & 31;
  StackParams P = s ? P1 : P0;
  const float* qr = emb + ((size_t)(((1 - s) << 3) + b)) * kH;
  float wi0 = P.inw[l * 3 + 0], wi1 = P.inw[l * 3 + 1], wi2 = P.inw[l * 3 + 2];
  float bi0 = P.inb[l * 3 + 0], bi1 = P.inb[l * 3 + 1], bi2 = P.inb[l * 3 + 2];
  float ow = P.ow[l], ob = P.ob[l];
  const float* g1 = P.g1 + (size_t)l * kH;
  const float* be1 = P.be1 + (size_t)l * kH;

  __shared__ float kvs[kH];
  __shared__ float2 kvp[kH];
  __shared__ float red[8];

  int t = threadIdx.x;
  float lsum = 0.f, lsq = 0.f;
  if (l == 0) {
    const float* kvr = kv0 + ((size_t)((s << 3) + b)) * kH;
#pragma unroll
    for (int i = 0; i < 4; ++i) {
      int n = t + 256 * i;
      float x = kvr[n];
      kvs[n] = x;
      lsum += x;
      lsq += x * x;
    }
  } else {
    const float* b2p = P.b2 + (size_t)(l - 1) * kH;
    const float* xr = xn + ((size_t)((s << 3) + b)) * kH;
    const float* pp = part2 + ((size_t)(s * 16) * kB + b) * kH;
#pragma unroll
    for (int i = 0; i < 4; ++i) {
      int n = t + 256 * i;
      float x = b2p[n] + xr[n];
#pragma unroll 4
      for (int p = 0; p < 16; ++p) x += pp[(size_t)p * kB * kH + n];
      kvs[n] = x;
      lsum += x;
      lsq += x * x;
    }
  }
  blkReduceSum2(lsum, lsq, red);
  float mean = lsum * (1.f / kH);
  float rstd = rsqrtf(lsq * (1.f / kH) - mean * mean + kEps);

  float lmax = -1e30f, lmin = 1e30f;
#pragma unroll
  for (int i = 0; i < 4; ++i) {
    int k = t + 256 * i;
    float x = kvs[k];
    float kp = fmaf(x, wi1, bi1);
    float v = (x - mean) * rstd * g1[k] + be1[k];
    float vp = fmaf(v, wi2, bi2);
    kvp[k] = make_float2(kp, vp);
    lmax = fmaxf(lmax, kp);
    lmin = fminf(lmin, kp);
  }
  blkReduceMaxMin(lmax, lmin, red);
  __syncthreads();

  int q = (qt << 5) + (t >> 3);
  int ks = t & 7;
  float sq = fmaf(qr[q], wi0, bi0);
  float mb = fmaxf(sq * lmax, sq * lmin);
  float den0 = 0.f, num0 = 0.f, den1 = 0.f, num1 = 0.f;
#pragma unroll 4
  for (int j = 0; j < 128; j += 2) {
    float2 a = kvp[ks + (j << 3)];
    float2 c = kvp[ks + ((j + 1) << 3)];
    float e0 = __expf(fmaf(sq, a.x, -mb));
    float e1 = __expf(fmaf(sq, c.x, -mb));
    den0 += e0; num0 = fmaf(e0, a.y, num0);
    den1 += e1; num1 = fmaf(e1, c.y, num1);
  }
  float den = den0 + den1, num = num0 + num1;
#pragma unroll
  for (int m = 1; m < 8; m <<= 1) {
    den += __shfl_xor(den, m);
    num += __shfl_xor(num, m);
  }
  if (ks == 0) {
    float av = num / den;
    float vq = (kvs[q] - mean) * rstd * g1[q] + be1[q];
    y2[((size_t)((s << 3) + b)) * kH + q] = fmaf(av, ow, ob) + vq;
  }
}

// Shared tile-reduce: acc[8][4] per thread (cq=t&15, rg=t>>4) -> t<128 holds
// float4 summed over all 16 rg; returns it (valid only for t<128).
__device__ __forceinline__ float4 tileReduce(float acc[kB][4], float* red, int t) {
#pragma unroll
  for (int b = 0; b < kB; ++b)
#pragma unroll
    for (int j = 0; j < 4; ++j) {
      float v = acc[b][j];
      v += __shfl_xor(v, 16);
      v += __shfl_xor(v, 32);
      acc[b][j] = v;
    }
  int wave = t >> 6, lane = t & 63;
  if (lane < 16) {
#pragma unroll
    for (int b = 0; b < kB; ++b) {
      float* p = red + (size_t)(wave * 16 + lane) * 40 + b * 4;
      p[0] = acc[b][0]; p[1] = acc[b][1]; p[2] = acc[b][2]; p[3] = acc[b][3];
    }
  }
  __syncthreads();
  float4 sum = make_float4(0.f, 0.f, 0.f, 0.f);
  if (t < 128) {
    int cq = t >> 3, b = t & 7;
#pragma unroll
    for (int w = 0; w < 4; ++w) {
      const float* p = red + (size_t)(w * 16 + cq) * 40 + b * 4;
      sum.x += p[0]; sum.y += p[1]; sum.z += p[2]; sum.w += p[3];
    }
  }
  return sum;
}

// LN2 + normalize + partial GEMV vs W1 (K split 4x256, in-block reduced).
__global__ __launch_bounds__(256) void gemm1Kernel(const float* __restrict__ y2,
                                                   float* __restrict__ xn,
                                                   float* __restrict__ part1,
                                                   StackParams P0, StackParams P1,
                                                   int l) {
  int bid = blockIdx.x;      // 512 = 2 s * 4 kc * 64 ft
  int s = bid >> 8;
  int kc = (bid >> 6) & 3;
  int ft = bid & 63;
  StackParams P = s ? P1 : P0;
  const float* y2s = y2 + ((size_t)s << 13);
  __shared__ float sm[kB], sr[kB];
  __shared__ float Xs[kB][256];
  __shared__ float red[64 * 40];
  int t = threadIdx.x;
  {
    int b = t >> 5, lane = t & 31;
    const float* row = y2s + (size_t)b * kH;
    float sum = 0.f, sq = 0.f;
    for (int i = lane; i < kH; i += 32) {
      float x = row[i];
      sum += x;
      sq += x * x;
    }
#pragma unroll
    for (int m = 1; m < 32; m <<= 1) { sum += __shfl_xor(sum, m); sq += __shfl_xor(sq, m); }
    if (lane == 0) {
      float mean = sum * (1.f / kH);
      sm[b] = mean;
      sr[b] = rsqrtf(sq * (1.f / kH) - mean * mean + kEps);
    }
  }
  __syncthreads();
  int k0 = kc << 8;
  const float* g2p = P.g2 + (size_t)l * kH + k0;
  const float* be2p = P.be2 + (size_t)l * kH + k0;
#pragma unroll
  for (int i = 0; i < 8; ++i) {
    int idx = t + 256 * i;
    int b = idx >> 8, kk = idx & 255;
    float x = y2s[(size_t)b * kH + k0 + kk];
    float v = (x - sm[b]) * sr[b] * g2p[kk] + be2p[kk];
    Xs[b][kk] = v;
    if (ft == 0) xn[((size_t)((s << 3) + b)) * kH + k0 + kk] = v;
  }
  __syncthreads();
  int cq = t & 15, rg = t >> 4;
  int c0 = (ft << 6) + (cq << 2);
  const float* W = P.W1 + (size_t)l * kH * kFF + (size_t)(k0 + rg) * kFF + c0;
  float acc[kB][4];
#pragma unroll
  for (int b = 0; b < kB; ++b)
#pragma unroll
    for (int j = 0; j < 4; ++j) acc[b][j] = 0.f;
#pragma unroll
  for (int i = 0; i < 16; ++i) {
    float4 w = *reinterpret_cast<const float4*>(W + (size_t)i * 16 * kFF);
    int r = rg + 16 * i;
#pragma unroll
    for (int b = 0; b < kB; ++b) {
      float x = Xs[b][r];
      acc[b][0] = fmaf(x, w.x, acc[b][0]);
      acc[b][1] = fmaf(x, w.y, acc[b][1]);
      acc[b][2] = fmaf(x, w.z, acc[b][2]);
      acc[b][3] = fmaf(x, w.w, acc[b][3]);
    }
  }
  float4 sum = tileReduce(acc, red, t);
  if (t < 128) {
    int cqq = t >> 3, b = t & 7;
    float* pp = part1 + ((size_t)((s * 4 + kc) * kB + b)) * kFF + (ft << 6) + (cqq << 2);
    *reinterpret_cast<float4*>(pp) = sum;
  }
}

// Reduce 4 part1 slices + bias + exact gelu, then partial GEMV vs W2
// (K split 16x256, in-block reduced).
__global__ __launch_bounds__(256) void gemm2Kernel(const float* __restrict__ part1,
                                                   float* __restrict__ part2,
                                                   StackParams P0, StackParams P1,
                                                   int l) {
  int bid = blockIdx.x;      // 512 = 2 s * 16 kc * 16 ft
  int s = bid >> 8;
  int kc = (bid >> 4) & 15;
  int ft = bid & 15;
  StackParams P = s ? P1 : P0;
  int k0 = kc << 8;
  __shared__ float Xs[kB][256];
  __shared__ float red[64 * 40];
  int t = threadIdx.x;
  const float* b1p = P.b1 + (size_t)l * kFF + k0;
#pragma unroll
  for (int i = 0; i < 8; ++i) {
    int idx = t + 256 * i;
    int b = idx >> 8, kk = idx & 255;
    const float* pp = part1 + ((size_t)(s * 4) * kB + b) * kFF + k0 + kk;
    float sum = b1p[kk];
#pragma unroll
    for (int p = 0; p < 4; ++p) sum += pp[(size_t)p * kB * kFF];
    Xs[b][kk] = 0.5f * sum * (1.f + erff(sum * 0.70710678118654752f));
  }
  __syncthreads();
  int cq = t & 15, rg = t >> 4;
  int c0 = (ft << 6) + (cq << 2);
  const float* W = P.W2 + (size_t)l * kFF * kH + (size_t)(k0 + rg) * kH + c0;
  float acc[kB][4];
#pragma unroll
  for (int b = 0; b < kB; ++b)
#pragma unroll
    for (int j = 0; j < 4; ++j) acc[b][j] = 0.f;
#pragma unroll
  for (int i = 0; i < 16; ++i) {
    float4 w = *reinterpret_cast<const float4*>(W + (size_t)i * 16 * kH);
    int r = rg + 16 * i;
#pragma unroll
    for (int b = 0; b < kB; ++b) {
      float x = Xs[b][r];
      acc[b][0] = fmaf(x, w.x, acc[b][0]);
      acc[b][1] = fmaf(x, w.y, acc[b][1]);
      acc[b][2] = fmaf(x, w.z, acc[b][2]);
      acc[b][3] = fmaf(x, w.w, acc[b][3]);
    }
  }
  float4 sum = tileReduce(acc, red, t);
  if (t < 128) {
    int cqq = t >> 3, b = t & 7;
    float* pp = part2 + ((size_t)((s * 16 + kc) * kB + b)) * kH + (ft << 6) + (cqq << 2);
    *reinterpret_cast<float4*>(pp) = sum;
  }
}

// Final: reconstruct kv(11) from part2 + b2 + xn, LN over concat(2048).
__global__ __launch_bounds__(1024) void finalLn(const float* __restrict__ part2,
                                                const float* __restrict__ xn,
                                                const float* __restrict__ g,
                                                const float* __restrict__ bb,
                                                StackParams P0, StackParams P1,
                                                float* __restrict__ out) {
  int b = blockIdx.x;   // 8
  int t = threadIdx.x;  // 1024
  __shared__ float red[32];
  float vals[2];
  float sum = 0.f, sq = 0.f;
#pragma unroll
  for (int i = 0; i < 2; ++i) {
    int s = i, n = t;
    StackParams P = s ? P1 : P0;
    float x = P.b2[(size_t)(kL - 1) * kH + n] + xn[((size_t)((s << 3) + b)) * kH + n];
    const float* pp = part2 + ((size_t)(s * 16) * kB + b) * kH + n;
#pragma unroll 4
    for (int p = 0; p < 16; ++p) x += pp[(size_t)p * kB * kH];
    vals[i] = x;
    sum += x;
    sq += x * x;
  }
#pragma unroll
  for (int m = 1; m < 64; m <<= 1) { sum += __shfl_xor(sum, m); sq += __shfl_xor(sq, m); }
  int w = t >> 6;
  if ((t & 63) == 0) { red[w] = sum; red[16 + w] = sq; }
  __syncthreads();
  sum = 0.f; sq = 0.f;
#pragma unroll
  for (int j = 0; j < 16; ++j) { sum += red[j]; sq += red[16 + j]; }
  float mean = sum * (1.f / 2048.f);
  float rstd = rsqrtf(sq * (1.f / 2048.f) - mean * mean + kEps);
#pragma unroll
  for (int i = 0; i < 2; ++i) {
    int idx = t + 1024 * i;
    out[(size_t)b * 2048 + idx] = (vals[i] - mean) * rstd * g[idx] + bb[idx];
  }
}

}  // namespace

extern "C" void kernel_launch(void* const* d_in, const int* in_sizes, int n_in,
                              void* d_out, int out_size, void* d_ws, size_t ws_size,
                              hipStream_t stream) {
  const float* ct = (const float*)d_in[0];
  const float* clinical = (const float*)d_in[1];
  const float* W_ct = (const float*)d_in[2];
  const float* b_ct = (const float*)d_in[3];
  const float* W_cl = (const float*)d_in[4];
  const float* b_cl = (const float*)d_in[5];
  const float* norm_g = (const float*)d_in[6];
  const float* norm_b = (const float*)d_in[7];

  StackParams P0{(const float*)d_in[8],  (const float*)d_in[9],  (const float*)d_in[10],
                 (const float*)d_in[11], (const float*)d_in[12], (const float*)d_in[13],
                 (const float*)d_in[14], (const float*)d_in[15], (const float*)d_in[16],
                 (const float*)d_in[17], (const float*)d_in[18], (const float*)d_in[19]};
  StackParams P1{(const float*)d_in[20], (const float*)d_in[21], (const float*)d_in[22],
                 (const float*)d_in[23], (const float*)d_in[24], (const float*)d_in[25],
                 (const float*)d_in[26], (const float*)d_in[27], (const float*)d_in[28],
                 (const float*)d_in[29], (const float*)d_in[30], (const float*)d_in[31]};

  float* ws = (float*)d_ws;
  float* emb = ws;                                    // [2][8][1024]
  float* kv0 = emb + 2 * kB * kH;                     // [2][8][1024]
  float* y2 = kv0 + 2 * kB * kH;                      // [2][8][1024]
  float* xn = y2 + 2 * kB * kH;                       // [2][8][1024]
  float* part1 = xn + 2 * kB * kH;                    // [2][4][8][4096]  = 1 MB
  float* part2 = part1 + (size_t)2 * 4 * kB * kFF;    // [2][16][8][1024] = 2 MB
  float* pct = part2 + (size_t)2 * 16 * kB * kH;      // [128][8][1024]   = 4 MB
  float* pcl = pct + (size_t)128 * kB * kH;           // [32][8][1024]    = 1 MB

  gemvPart<16><<<128, 256, 0, stream>>>(ct, W_ct, pct, 2048, 1024);
  gemvPart<4><<<32, 256, 0, stream>>>(clinical, W_cl, pcl, 128, 1024);
  embedReduce<<<64, 256, 0, stream>>>(pct, pcl, b_ct, b_cl, emb, kv0);

  for (int l = 0; l < kL; ++l) {
    attnKernel<<<512, 256, 0, stream>>>(kv0, part2, xn, emb, y2, P0, P1, l);
    gemm1Kernel<<<512, 256, 0, stream>>>(y2, xn, part1, P0, P1, l);
    gemm2Kernel<<<512, 256, 0, stream>>>(part1, part2, P0, P1, l);
  }

  finalLn<<<8, 1024, 0, stream>>>(part2, xn, norm_g, norm_b, P0, P1, (float*)d_out);
}